// Round 6
// baseline (653.503 us; speedup 1.0000x reference)
//
#include <hip/hip_runtime.h>
#include <cstdint>

// PQDenseLayer: out[b,d] = sum_m ( x[b, m*128:+128] @ W[m] + bias[m] )[ idx[m,d] ]
// Two kernels per B-chunk:
//   K1: proj[m][k][b]  (f32 batched GEMM, VALU-bound, ~109us fp32 floor total;
//       LDS traffic is broadcast-dominated -> ~16 B/cyc/CU unique, not binding)
//   K2: LDS-staged gather-sum (ds_read_b128 over b-quads; per 8-lane group one
//       128B row = all 32 banks exactly once -> conflict-free without swizzle;
//       idx software-pipelined one m ahead to hide L2 latency)

#define M_CB   32
#define CHUNK_C 128
#define KS_K   256
#define DIN    4096

// direct global->LDS (wave-uniform LDS base + lane*16; per-lane global addr)
#define GLOAD_LDS16(gp, lp)                                                      \
  __builtin_amdgcn_global_load_lds(                                              \
      (const __attribute__((address_space(1))) void*)(gp),                       \
      (__attribute__((address_space(3))) void*)(lp), 16, 0, 0)

// ---------------------------------------------------------------------------
// K1: batched GEMM. grid = (Bc/64, M), block = 256.
// thread: bq = t&15 (b-quad), g = t>>4 (16 k's: k = g*16 + j)
// LDS: xs transposed [c][68] (68 = 4 mod 32 -> x-stage writes 4-way (noise),
//      compute reads 2-way+broadcast = free), Wl [c][256] staged linearly
//      via global_load_lds width-16. 40.5 KB -> 3 blocks/CU (12 waves).
// ---------------------------------------------------------------------------
__global__ __launch_bounds__(256, 3)
void k1_gemm(const float* __restrict__ x, const float* __restrict__ W,
             const float* __restrict__ bias, float* __restrict__ proj,
             int b0_chunk, int Bc) {
  const int t  = threadIdx.x;
  const int bq = t & 15;
  const int g  = t >> 4;
  const int m  = blockIdx.y;
  const int bb = blockIdx.x * 64;

  __shared__ float xs[32 * 68];     // 8.5 KB
  __shared__ float Wl[32 * 256];    // 32 KB

  float4 acc[16];
  // init with bias (broadcast across the b-quad)
#pragma unroll
  for (int a = 0; a < 4; ++a) {
    float4 bv = *(const float4*)&bias[m * KS_K + g * 16 + 4 * a];
    acc[4 * a + 0] = make_float4(bv.x, bv.x, bv.x, bv.x);
    acc[4 * a + 1] = make_float4(bv.y, bv.y, bv.y, bv.y);
    acc[4 * a + 2] = make_float4(bv.z, bv.z, bv.z, bv.z);
    acc[4 * a + 3] = make_float4(bv.w, bv.w, bv.w, bv.w);
  }

  const float* xg = x + (size_t)(b0_chunk + bb) * DIN + m * CHUNK_C;
  const float* Wg = W + (size_t)m * CHUNK_C * KS_K;

  for (int cc = 0; cc < 4; ++cc) {          // 4 chunks of 32 c's
    __syncthreads();                        // previous compute done reading LDS
    // stage W chunk: 32 rows x 256 k = 32KB, linear copy, 2048 16B chunks
    {
      const float* src = Wg + (size_t)(cc * 32) * KS_K;
      const int wb = (t & ~63);             // wave-uniform LDS base
#pragma unroll
      for (int i = 0; i < 8; ++i) {
        const int C = t + 256 * i;          // global 16B chunk index
        GLOAD_LDS16(src + 4 * C, (char*)Wl + (size_t)(wb + 256 * i) * 16);
      }
    }
    // stage x chunk transposed: read float4 along c, scatter 4 ds_writes
#pragma unroll
    for (int i = 0; i < 2; ++i) {
      const int f = t + 256 * i;            // 512 float4 = 64b x 32c
      const int b = f >> 3, cq = f & 7;
      float4 v = *(const float4*)&xg[(size_t)b * DIN + cc * 32 + 4 * cq];
      xs[(4 * cq + 0) * 68 + b] = v.x;
      xs[(4 * cq + 1) * 68 + b] = v.y;
      xs[(4 * cq + 2) * 68 + b] = v.z;
      xs[(4 * cq + 3) * 68 + b] = v.w;
    }
    asm volatile("s_waitcnt vmcnt(0)" ::: "memory");
    __syncthreads();

#define FMA4(J, S)                                      \
  {                                                     \
    acc[J].x = fmaf(xq.x, (S), acc[J].x);               \
    acc[J].y = fmaf(xq.y, (S), acc[J].y);               \
    acc[J].z = fmaf(xq.z, (S), acc[J].z);               \
    acc[J].w = fmaf(xq.w, (S), acc[J].w);               \
  }
#pragma unroll 2
    for (int c = 0; c < 32; ++c) {
      float4 xq = *(float4*)&xs[c * 68 + 4 * bq];
      float4 w0 = *(float4*)&Wl[c * 256 + g * 16 + 0];
      float4 w1 = *(float4*)&Wl[c * 256 + g * 16 + 4];
      float4 w2 = *(float4*)&Wl[c * 256 + g * 16 + 8];
      float4 w3 = *(float4*)&Wl[c * 256 + g * 16 + 12];
      FMA4(0, w0.x)  FMA4(1, w0.y)  FMA4(2, w0.z)  FMA4(3, w0.w)
      FMA4(4, w1.x)  FMA4(5, w1.y)  FMA4(6, w1.z)  FMA4(7, w1.w)
      FMA4(8, w2.x)  FMA4(9, w2.y)  FMA4(10, w2.z) FMA4(11, w2.w)
      FMA4(12, w3.x) FMA4(13, w3.y) FMA4(14, w3.z) FMA4(15, w3.w)
    }
#undef FMA4
  }

  // store proj[m][k][b] (b contiguous; per instr: 4 g-groups x 256B segments)
#pragma unroll
  for (int j = 0; j < 16; ++j) {
    const int k = g * 16 + j;
    *(float4*)&proj[((size_t)m * KS_K + k) * Bc + bb + 4 * bq] = acc[j];
  }
}

// ---------------------------------------------------------------------------
// K2: gather-sum. grid = (Bc/32, D_out/2048), block = 512.
// thread: q = t&7 (b-quad within 32-row tile), g = t>>3 (0..63),
//         d = dbase + 0..31 consecutive; acc = 32 float4 (b-quad per d).
// LDS: double-buffered proj tile [k=256][b=32] f32, linear layout.
// idx for m+1 prefetched alongside STAGE(m+1); end-of-loop vmcnt(0) (needed
// for the stage anyway) drains it for free.
// ---------------------------------------------------------------------------
__global__ __launch_bounds__(512, 2)
void k2_gather(const float* __restrict__ proj, const int* __restrict__ idx,
               float* __restrict__ out, int b0_chunk, int Bc, int D_out) {
  const int t  = threadIdx.x;
  const int q  = t & 7;
  const int g  = t >> 3;
  const int b0 = blockIdx.x * 32;
  const int dbase = blockIdx.y * 2048 + g * 32;

  __shared__ float pb[2][8192];   // 2 x 32KB

  float4 acc[32];
#pragma unroll
  for (int j = 0; j < 32; ++j) acc[j] = make_float4(0.f, 0.f, 0.f, 0.f);

  const int q16 = q << 4;
  const int* ixp = idx + dbase;   // advance by D_out per m

#define STAGE(MM, BUF)                                                          \
  {                                                                             \
    const float* src_ = proj + (size_t)(MM)*KS_K * Bc + b0;                     \
    const int wb_ = (t & ~63);                                                  \
    _Pragma("unroll") for (int i_ = 0; i_ < 4; ++i_) {                          \
      const int C_ = t + 512 * i_; /* 2048 chunks of 16B, linear */             \
      const int k_ = C_ >> 3, qp_ = C_ & 7;                                     \
      GLOAD_LDS16(src_ + (size_t)k_ * Bc + 4 * qp_,                             \
                  (char*)(BUF) + (size_t)(wb_ + 512 * i_) * 16);                \
    }                                                                           \
  }

  // prologue: stage m=0 and preload idx row 0
  STAGE(0, pb[0]);
  int4 iv[8];
#pragma unroll
  for (int a = 0; a < 8; ++a) iv[a] = *(const int4*)&ixp[4 * a];
  asm volatile("s_waitcnt vmcnt(0)" ::: "memory");
  __syncthreads();

  int cur = 0;
  for (int m = 0; m < M_CB; ++m) {
    // prefetch next m's idx row + proj tile (both drained by loop-end vmcnt(0))
    int4 ivn[8];
    if (m < M_CB - 1) {
      const int* ixn = ixp + (size_t)(m + 1) * D_out;
#pragma unroll
      for (int a = 0; a < 8; ++a) ivn[a] = *(const int4*)&ixn[4 * a];
      STAGE(m + 1, pb[cur ^ 1]);
    }

    const char* pbase = (const char*)&pb[cur][0] + q16;
#define GSTEP(KV, J)                                                            \
  {                                                                             \
    const float4 v_ = *(const float4*)(pbase + ((KV) << 7));                    \
    acc[J].x += v_.x; acc[J].y += v_.y; acc[J].z += v_.z; acc[J].w += v_.w;     \
  }
#pragma unroll
    for (int a = 0; a < 8; ++a) {
      GSTEP(iv[a].x, 4 * a + 0)
      GSTEP(iv[a].y, 4 * a + 1)
      GSTEP(iv[a].z, 4 * a + 2)
      GSTEP(iv[a].w, 4 * a + 3)
    }
#undef GSTEP
    asm volatile("s_waitcnt vmcnt(0)" ::: "memory");
    __syncthreads();
    if (m < M_CB - 1) {
#pragma unroll
      for (int a = 0; a < 8; ++a) iv[a] = ivn[a];
    }
    cur ^= 1;
  }
#undef STAGE

  // epilogue: register transpose -> d-major dwordx4 stores; across a=0..7 each
  // (b-row, g) assembles one full 128B line -> L2 write-combining
  float* op = out + (size_t)(b0_chunk + b0 + 4 * q) * D_out + dbase;
#pragma unroll
  for (int a = 0; a < 8; ++a) {
    float4 o0 = make_float4(acc[4*a+0].x, acc[4*a+1].x, acc[4*a+2].x, acc[4*a+3].x);
    float4 o1 = make_float4(acc[4*a+0].y, acc[4*a+1].y, acc[4*a+2].y, acc[4*a+3].y);
    float4 o2 = make_float4(acc[4*a+0].z, acc[4*a+1].z, acc[4*a+2].z, acc[4*a+3].z);
    float4 o3 = make_float4(acc[4*a+0].w, acc[4*a+1].w, acc[4*a+2].w, acc[4*a+3].w);
    *(float4*)(op + 0 * (size_t)D_out + 4 * a) = o0;
    *(float4*)(op + 1 * (size_t)D_out + 4 * a) = o1;
    *(float4*)(op + 2 * (size_t)D_out + 4 * a) = o2;
    *(float4*)(op + 3 * (size_t)D_out + 4 * a) = o3;
  }
}

// ---------------------------------------------------------------------------
extern "C" void kernel_launch(void* const* d_in, const int* in_sizes, int n_in,
                              void* d_out, int out_size, void* d_ws, size_t ws_size,
                              hipStream_t stream) {
  const float* x    = (const float*)d_in[0];
  const float* W    = (const float*)d_in[1];
  const float* bias = (const float*)d_in[2];
  const int*   idx  = (const int*)d_in[3];
  float* out  = (float*)d_out;
  float* proj = (float*)d_ws;

  const int B     = in_sizes[0] / DIN;          // 8192
  const int D_out = in_sizes[3] / M_CB;         // 4096

  // B-chunk sized to workspace; prefer 4096 (proj chunk = 128 MB <= L3,
  // K2's 2 read passes get absorbed by Infinity Cache)
  size_t maxBc = ws_size / ((size_t)M_CB * KS_K * sizeof(float));
  int Bc = 4096;
  if ((size_t)Bc > maxBc) Bc = (int)(maxBc & ~(size_t)63);
  if (Bc > B) Bc = B;
  if (Bc < 64) Bc = 64;

  for (int b0 = 0; b0 < B; b0 += Bc) {
    int cb = (B - b0 < Bc) ? (B - b0) : Bc;
    dim3 g1(cb / 64, M_CB);
    k1_gemm<<<g1, 256, 0, stream>>>(x, W, bias, proj, b0, cb);
    dim3 g2(cb / 32, D_out / 2048);
    k2_gather<<<g2, 512, 0, stream>>>(proj, idx, out, b0, cb, D_out);
  }
}